// Round 1
// baseline (458.926 us; speedup 1.0000x reference)
//
#include <hip/hip_runtime.h>

// Problem constants: B=2, L=4096, D_IN=256, D_OUT=256, K=16
// out[b,l,p] = sum_k lam[k] * sum_m ev[k,(l-m)%L] * (sum_d u[b,m,d]*M[k,d,p])
//
// Stage A: V[b, k*256+p, m] = sum_d u[b,m,d] * M[k,d,p]   (f32 tiled GEMM)
// Stage B: out[b,:,p] = sum_k lam_k * circconv(V[b,kp,:], ev[k,:]) via LDS FFT,
//          two p's packed per complex FFT, k-sum accumulated in frequency.

#define NFFT 4096
#define LOGN 12

// ---------------------------------------------------------------------------
// Stockham radix-2 DIF FFT, length 4096, autosorting (no bit reversal).
// src/dst are LDS float2 arrays of 4096; tw[t] = exp(-2*pi*i*t/4096), t<2048.
// After 12 stages (even count) the result is back in `a`, natural order.
// Caller must __syncthreads() after filling `a`; fft ends with a barrier.
// ---------------------------------------------------------------------------
__device__ __forceinline__ void fft4096(float2* a, float2* b,
                                        const float2* tw, int tid) {
  float2* src = a;
  float2* dst = b;
#pragma unroll
  for (int s = 0; s < LOGN; ++s) {
#pragma unroll
    for (int it = 0; it < 8; ++it) {
      int idx = tid + it * 256;              // butterfly id, 0..2047
      int jm  = (idx >> s) << s;             // j * m  (m = 1<<s)
      float2 x = src[idx];
      float2 y = src[idx + 2048];
      float2 w = tw[jm];                     // exp(-2pi*i * j / (2l)) = tw[j<<s]
      float xr = x.x - y.x, xi = x.y - y.y;
      dst[idx + jm] = make_float2(x.x + y.x, x.y + y.y);
      dst[idx + jm + (1 << s)] =
          make_float2(xr * w.x - xi * w.y, xr * w.y + xi * w.x);
    }
    __syncthreads();
    float2* t = src; src = dst; dst = t;
  }
}

__device__ __forceinline__ void build_tw(float2* tw, int tid) {
  for (int t = tid; t < 2048; t += 256) {
    float ang = -(float)t * (6.283185307179586f / 4096.0f);
    float s, c;
    sincosf(ang, &s, &c);
    tw[t] = make_float2(c, s);
  }
}

// ---------------------------------------------------------------------------
// Kernel 0: H[k,f] = lam[k]/4096 * DFT(ev[k])[f]   (full 4096-bin spectrum)
// ---------------------------------------------------------------------------
__global__ __launch_bounds__(256) void ev_dft(const float* __restrict__ ev,
                                              const float* __restrict__ lam,
                                              float2* __restrict__ H) {
  __shared__ float2 A[NFFT];
  __shared__ float2 Bb[NFFT];
  __shared__ float2 tw[2048];
  int tid = threadIdx.x;
  int k = blockIdx.x;
  build_tw(tw, tid);
  for (int l = tid; l < NFFT; l += 256)
    A[l] = make_float2(ev[(size_t)k * NFFT + l], 0.0f);
  __syncthreads();
  fft4096(A, Bb, tw, tid);
  float sc = lam[k] * (1.0f / 4096.0f);
  for (int f = tid; f < NFFT; f += 256) {
    float2 x = A[f];
    H[(size_t)k * NFFT + f] = make_float2(sc * x.x, sc * x.y);
  }
}

// ---------------------------------------------------------------------------
// Stage A: f32 GEMM.  V[plane=zb][kp][m] = sum_d u[bbase+zb, m, d] * M[k,d,p]
// Tile: BM=128 (m) x BN=128 (kp) x BK=16.  256 threads, 8x8 micro-tile.
// ---------------------------------------------------------------------------
#define BM 128
#define BN 128
#define BKK 16

__global__ __launch_bounds__(256) void gemm_v(const float* __restrict__ u,
                                              const float* __restrict__ M,
                                              float* __restrict__ V, int bbase) {
  __shared__ float As[BKK][BM + 4];   // As[d][m]  (u-tile, transposed on write)
  __shared__ float Bs[BKK][BN + 4];   // Bs[d][p'] (M-tile, direct)
  const int m0  = blockIdx.x * BM;
  const int kp0 = blockIdx.y * BN;
  const int k   = kp0 >> 8;           // 128 | 256 so a tile stays within one k
  const int p0  = kp0 & 255;
  const int tid = threadIdx.x;
  const int tm  = tid & 15;           // m sub-block
  const int tp  = tid >> 4;           // kp sub-block
  const int b   = bbase + blockIdx.z;

  float acc[8][8];                    // [kp][m]
#pragma unroll
  for (int j = 0; j < 8; ++j)
#pragma unroll
    for (int i = 0; i < 8; ++i) acc[j][i] = 0.0f;

  const float* ub = u + (size_t)b * NFFT * 256;
  const float* Mk = M + (size_t)k * 65536;

  for (int d0 = 0; d0 < 256; d0 += BKK) {
    // u tile: 128 m x 16 d, coalesced float4 reads, transposed into As
#pragma unroll
    for (int t = 0; t < 2; ++t) {
      int idx = tid + t * 256;              // 0..511
      int r   = idx >> 2;                   // m row 0..127
      int c4  = (idx & 3) * 4;              // d col
      const float4 v =
          *(const float4*)(ub + (size_t)(m0 + r) * 256 + d0 + c4);
      As[c4 + 0][r] = v.x;
      As[c4 + 1][r] = v.y;
      As[c4 + 2][r] = v.z;
      As[c4 + 3][r] = v.w;
    }
    // M tile: 16 d x 128 p, coalesced float4 reads, direct into Bs
#pragma unroll
    for (int t = 0; t < 2; ++t) {
      int idx = tid + t * 256;
      int r   = idx >> 5;                   // d row 0..15
      int c4  = (idx & 31) * 4;             // p col
      const float4 v =
          *(const float4*)(Mk + (size_t)(d0 + r) * 256 + p0 + c4);
      *(float4*)&Bs[r][c4] = v;
    }
    __syncthreads();
#pragma unroll
    for (int dd = 0; dd < BKK; ++dd) {
      float am[8], bp[8];
      *(float4*)&am[0] = *(const float4*)&As[dd][tm * 8];
      *(float4*)&am[4] = *(const float4*)&As[dd][tm * 8 + 4];
      *(float4*)&bp[0] = *(const float4*)&Bs[dd][tp * 8];
      *(float4*)&bp[4] = *(const float4*)&Bs[dd][tp * 8 + 4];
#pragma unroll
      for (int j = 0; j < 8; ++j)
#pragma unroll
        for (int i = 0; i < 8; ++i) acc[j][i] += bp[j] * am[i];
    }
    __syncthreads();
  }

  float* Vp = V + (size_t)blockIdx.z * NFFT * NFFT;
#pragma unroll
  for (int j = 0; j < 8; ++j) {
    int kp = kp0 + tp * 8 + j;
    float* dst = Vp + (size_t)kp * NFFT + m0 + tm * 8;
    *(float4*)dst = make_float4(acc[j][0], acc[j][1], acc[j][2], acc[j][3]);
    *(float4*)(dst + 4) =
        make_float4(acc[j][4], acc[j][5], acc[j][6], acc[j][7]);
  }
}

// ---------------------------------------------------------------------------
// Stage B: per (b, p-pair) workgroup.
//   x = V[b,k,p0,:] + i*V[b,k,p1,:];  X = FFT(x);  C += H_k * X  (over k)
//   y = FFT(conj(C));  out[b,l,p0] = Re(y), out[b,l,p1] = -Im(y)
// ---------------------------------------------------------------------------
__global__ __launch_bounds__(256) void conv_combine(
    const float* __restrict__ V, const float2* __restrict__ H,
    float* __restrict__ out, int bbase) {
  __shared__ float2 A[NFFT];     // work ping
  __shared__ float2 Bb[NFFT];    // work pong
  __shared__ float2 Cc[NFFT];    // frequency-domain accumulator
  __shared__ float2 tw[2048];
  const int tid = threadIdx.x;
  const int p0  = blockIdx.x * 2;
  const int b   = bbase + blockIdx.y;
  const float* Vp = V + (size_t)blockIdx.y * NFFT * NFFT;

  build_tw(tw, tid);
  for (int f = tid; f < NFFT; f += 256) Cc[f] = make_float2(0.0f, 0.0f);

  for (int k = 0; k < 16; ++k) {
    const float* v0 = Vp + (size_t)(k * 256 + p0) * NFFT;
    const float* v1 = v0 + NFFT;
    __syncthreads();  // prev MAC done reading A (k=0: tw/Cc ready)
    for (int l = tid; l < NFFT; l += 256)
      A[l] = make_float2(v0[l], v1[l]);
    __syncthreads();
    fft4096(A, Bb, tw, tid);
    const float2* Hk = H + (size_t)k * NFFT;
    for (int f = tid; f < NFFT; f += 256) {
      float2 x = A[f], h = Hk[f], c = Cc[f];
      c.x += h.x * x.x - h.y * x.y;
      c.y += h.x * x.y + h.y * x.x;
      Cc[f] = c;
    }
  }
  __syncthreads();
  for (int f = tid; f < NFFT; f += 256)
    A[f] = make_float2(Cc[f].x, -Cc[f].y);   // conj(C)
  __syncthreads();
  fft4096(A, Bb, tw, tid);

  float* ob = out + (size_t)b * NFFT * 256;
  for (int l = tid; l < NFFT; l += 256) {
    float2 y = A[l];
    *(float2*)(ob + (size_t)l * 256 + p0) = make_float2(y.x, -y.y);
  }
}

// ---------------------------------------------------------------------------
extern "C" void kernel_launch(void* const* d_in, const int* in_sizes, int n_in,
                              void* d_out, int out_size, void* d_ws,
                              size_t ws_size, hipStream_t stream) {
  const float* u   = (const float*)d_in[0];  // (2, 4096, 256)
  const float* ev  = (const float*)d_in[1];  // (16, 4096)
  const float* lam = (const float*)d_in[2];  // (16,)
  const float* M   = (const float*)d_in[3];  // (16, 256, 256)
  float* out = (float*)d_out;                // (2, 4096, 256)

  const size_t hBytes = (size_t)16 * NFFT * sizeof(float2);   // 512 KB
  const size_t planeB = (size_t)NFFT * NFFT * sizeof(float);  // 64 MB
  float2* H = (float2*)d_ws;
  float*  V = (float*)((char*)d_ws + hBytes);

  ev_dft<<<16, 256, 0, stream>>>(ev, lam, H);

  if (ws_size >= hBytes + 2 * planeB) {
    // both b planes resident: full-GPU conv pass (256 wgs)
    gemm_v<<<dim3(32, 32, 2), 256, 0, stream>>>(u, M, V, 0);
    conv_combine<<<dim3(128, 2), 256, 0, stream>>>(V, H, out, 0);
  } else {
    // fallback: one b plane at a time (needs 64.5 MB of ws)
    for (int b = 0; b < 2; ++b) {
      gemm_v<<<dim3(32, 32, 1), 256, 0, stream>>>(u, M, V, b);
      conv_combine<<<dim3(128, 1), 256, 0, stream>>>(V, H, out, b);
    }
  }
}

// Round 2
// 192.564 us; speedup vs baseline: 2.3832x; 2.3832x over previous
//
#include <hip/hip_runtime.h>

// B=2, L=4096, D_IN=256, D_OUT=256, K=16
// out[b,l,p] = sum_k lam_k * sum_m ev[k,(l-m)%L] * (sum_d u[b,m,d]*M[k,d,p])
// Stage A (MFMA bf16): V[plane][kp][m] = sum_d u[b,m,d]*M[k,d,p]  (bf16 store)
// Stage B (radix-4 Stockham FFT in LDS): out[b,:,p] via freq-domain k-sum,
//   two p's packed per complex FFT, C accumulated in registers.

typedef unsigned int uint;
using u16x8 = __attribute__((ext_vector_type(8))) unsigned short;
using s16x8 = __attribute__((ext_vector_type(8))) short;
using f32x4 = __attribute__((ext_vector_type(4))) float;

__device__ __forceinline__ unsigned short f2bf(float f) {
  uint u = __float_as_uint(f);
  uint r = (u + 0x7FFF + ((u >> 16) & 1)) >> 16;   // RNE
  return (unsigned short)r;
}
__device__ __forceinline__ float bf2f(unsigned short h) {
  return __uint_as_float(((uint)h) << 16);
}

// ---------------------------------------------------------------------------
// Radix-4 Stockham DIF FFT, N=4096, 6 stages, autosort; result back in `a`.
// tw[t] = exp(-2*pi*i*t/4096), t<1024 (w2,w3 computed from w1).
// Derived by composing two verified radix-2 Stockham stages:
//   p=idx; a,b,c,d = src[p], src[p+1024], src[p+2048], src[p+3072]
//   y0=(a+c)+(b+d); y1=w1*((a-c)-i(b-d)); y2=w1^2*((a+c)-(b+d)); y3=w1^3*((a-c)+i(b-d))
//   dst[idx+3*jm + {0,m,2m,3m}] = y0..y3,  jm = idx with low s bits cleared.
// ---------------------------------------------------------------------------
template <int NT>
__device__ __forceinline__ void fft4096(float2* __restrict__ a,
                                        float2* __restrict__ b,
                                        const float2* __restrict__ tw, int tid) {
  float2* src = a;
  float2* dst = b;
#pragma unroll
  for (int s = 0; s < 12; s += 2) {
    const int m = 1 << s;
#pragma unroll
    for (int it = 0; it < 1024 / NT; ++it) {
      int idx = tid + it * NT;                 // 0..1023
      int i   = idx & (m - 1);
      int jm  = idx - i;                       // (idx>>s)<<s, < 1024
      float2 A0 = src[idx];
      float2 B0 = src[idx + 1024];
      float2 C0 = src[idx + 2048];
      float2 D0 = src[idx + 3072];
      float2 w1 = tw[jm];
      float2 w2 = make_float2(w1.x * w1.x - w1.y * w1.y, 2.f * w1.x * w1.y);
      float2 w3 = make_float2(w2.x * w1.x - w2.y * w1.y, w2.x * w1.y + w2.y * w1.x);
      float acx = A0.x + C0.x, acy = A0.y + C0.y;
      float amx = A0.x - C0.x, amy = A0.y - C0.y;
      float bdx = B0.x + D0.x, bdy = B0.y + D0.y;
      float bmx = B0.x - D0.x, bmy = B0.y - D0.y;
      float2 y0 = make_float2(acx + bdx, acy + bdy);
      float2 t2 = make_float2(acx - bdx, acy - bdy);
      float2 t1 = make_float2(amx + bmy, amy - bmx);   // (a-c) - i(b-d)
      float2 t3 = make_float2(amx - bmy, amy + bmx);   // (a-c) + i(b-d)
      int base = idx + 3 * jm;
      dst[base]         = y0;
      dst[base + m]     = make_float2(w1.x * t1.x - w1.y * t1.y, w1.x * t1.y + w1.y * t1.x);
      dst[base + 2 * m] = make_float2(w2.x * t2.x - w2.y * t2.y, w2.x * t2.y + w2.y * t2.x);
      dst[base + 3 * m] = make_float2(w3.x * t3.x - w3.y * t3.y, w3.x * t3.y + w3.y * t3.x);
    }
    __syncthreads();
    float2* t = src; src = dst; dst = t;
  }
}

template <int NT>
__device__ __forceinline__ void build_tw(float2* tw, int tid) {
  for (int t = tid; t < 1024; t += NT) {
    float ang = -(float)t * (6.283185307179586f / 4096.0f);
    float s, c;
    sincosf(ang, &s, &c);
    tw[t] = make_float2(c, s);
  }
}

// ---------------------------------------------------------------------------
// Prep: u f32 -> bf16 (same layout); M[k][d][p] f32 -> Mt[k][p][d] bf16
// ---------------------------------------------------------------------------
__global__ __launch_bounds__(256) void cvt_u(const float* __restrict__ u,
                                             unsigned short* __restrict__ ub) {
  size_t i = ((size_t)blockIdx.x * 256 + threadIdx.x) * 8;
  float4 a = *(const float4*)(u + i);
  float4 b = *(const float4*)(u + i + 4);
  u16x8 o;
  o[0] = f2bf(a.x); o[1] = f2bf(a.y); o[2] = f2bf(a.z); o[3] = f2bf(a.w);
  o[4] = f2bf(b.x); o[5] = f2bf(b.y); o[6] = f2bf(b.z); o[7] = f2bf(b.w);
  *(u16x8*)(ub + i) = o;
}

__global__ __launch_bounds__(256) void tr_M(const float* __restrict__ M,
                                            unsigned short* __restrict__ Mt) {
  __shared__ float t[64][65];
  const int k = blockIdx.z, d0 = blockIdx.x * 64, p0 = blockIdx.y * 64;
  const int r = threadIdx.x >> 2, c0 = (threadIdx.x & 3) * 16;
  const float* src = M + ((size_t)k * 256 + d0) * 256 + p0;
#pragma unroll
  for (int j = 0; j < 4; ++j) {
    float4 v = *(const float4*)(src + (size_t)r * 256 + c0 + j * 4);
    t[r][c0 + j * 4 + 0] = v.x;
    t[r][c0 + j * 4 + 1] = v.y;
    t[r][c0 + j * 4 + 2] = v.z;
    t[r][c0 + j * 4 + 3] = v.w;
  }
  __syncthreads();
  // Mt[k][p0+r][d0+c0+j] = t[c0+j][r]
  u16x8 o0, o1;
#pragma unroll
  for (int j = 0; j < 8; ++j) o0[j] = f2bf(t[c0 + j][r]);
#pragma unroll
  for (int j = 0; j < 8; ++j) o1[j] = f2bf(t[c0 + 8 + j][r]);
  unsigned short* dst = Mt + ((size_t)k * 256 + p0 + r) * 256 + d0 + c0;
  *(u16x8*)dst = o0;
  *(u16x8*)(dst + 8) = o1;
}

// ---------------------------------------------------------------------------
// H[k,f] = lam[k]/4096 * DFT(ev[k])[f]
// ---------------------------------------------------------------------------
__global__ __launch_bounds__(256) void ev_dft(const float* __restrict__ ev,
                                              const float* __restrict__ lam,
                                              float2* __restrict__ H) {
  __shared__ float2 A[4096];
  __shared__ float2 Bb[4096];
  __shared__ float2 tw[1024];
  const int tid = threadIdx.x, k = blockIdx.x;
  build_tw<256>(tw, tid);
  for (int l = tid; l < 4096; l += 256)
    A[l] = make_float2(ev[(size_t)k * 4096 + l], 0.0f);
  __syncthreads();
  fft4096<256>(A, Bb, tw, tid);
  float sc = lam[k] * (1.0f / 4096.0f);
  for (int f = tid; f < 4096; f += 256) {
    float2 x = A[f];
    H[(size_t)k * 4096 + f] = make_float2(sc * x.x, sc * x.y);
  }
}

// ---------------------------------------------------------------------------
// Stage A: bf16 MFMA GEMM.  V[z][kp][m] = sum_d ub[b,m,d]*Mt[k,p,d]
// 128x128 tile, BK=64, 4 waves (2x2, each 64x64 = 4x4 frags of 16x16x32).
// LDS: As/Bs [row=128][k=64] bf16, 16B-slot XOR swizzle (slot ^= row&7) so
// fragment ds_read_b128 and staging ds_write_b128 are conflict-free.
// ---------------------------------------------------------------------------
__global__ __launch_bounds__(256) void gemm_mfma(const unsigned short* __restrict__ ub,
                                                 const unsigned short* __restrict__ Mt,
                                                 unsigned short* __restrict__ V,
                                                 int bbase) {
  __shared__ unsigned short As[128 * 64];
  __shared__ unsigned short Bs[128 * 64];
  const int m0  = blockIdx.x * 128;
  const int kp0 = blockIdx.y * 128;
  const int k   = kp0 >> 8;
  const int p0  = kp0 & 255;
  const int tid = threadIdx.x;
  const int lane = tid & 63;
  const int wave = tid >> 6;
  const int wm = wave >> 1, wn = wave & 1;

  f32x4 acc[4][4];
#pragma unroll
  for (int a = 0; a < 4; ++a)
#pragma unroll
    for (int b = 0; b < 4; ++b) acc[a][b] = (f32x4){0.f, 0.f, 0.f, 0.f};

  const unsigned short* uB = ub + (size_t)(bbase + blockIdx.z) * 4096 * 256;
  const unsigned short* mB = Mt + (size_t)k * 65536 + (size_t)p0 * 256;

  for (int d0 = 0; d0 < 256; d0 += 64) {
#pragma unroll
    for (int t = 0; t < 4; ++t) {
      int c = tid + t * 256;            // 1024 16B-chunks per tile
      int row = c >> 3, slot = c & 7;
      u16x8 va = *(const u16x8*)(uB + (size_t)(m0 + row) * 256 + d0 + slot * 8);
      u16x8 vb = *(const u16x8*)(mB + (size_t)row * 256 + d0 + slot * 8);
      int ss = slot ^ (row & 7);
      *(u16x8*)(&As[row * 64 + ss * 8]) = va;
      *(u16x8*)(&Bs[row * 64 + ss * 8]) = vb;
    }
    __syncthreads();
#pragma unroll
    for (int kk = 0; kk < 2; ++kk) {
      const int kslot = kk * 4 + (lane >> 4);
      s16x8 af[4], bfr[4];
#pragma unroll
      for (int mf = 0; mf < 4; ++mf) {
        int row = wm * 64 + mf * 16 + (lane & 15);
        af[mf] = *(const s16x8*)(&As[row * 64 + (kslot ^ (row & 7)) * 8]);
      }
#pragma unroll
      for (int nf = 0; nf < 4; ++nf) {
        int row = wn * 64 + nf * 16 + (lane & 15);
        bfr[nf] = *(const s16x8*)(&Bs[row * 64 + (kslot ^ (row & 7)) * 8]);
      }
#pragma unroll
      for (int mf = 0; mf < 4; ++mf)
#pragma unroll
        for (int nf = 0; nf < 4; ++nf)
          acc[mf][nf] = __builtin_amdgcn_mfma_f32_16x16x32_bf16(
              af[mf], bfr[nf], acc[mf][nf], 0, 0, 0);
    }
    __syncthreads();
  }

  // C/D layout (verified m89/m91): col=lane&15 (kp), row=(lane>>4)*4+i (m).
  // Store V[kp][m] bf16: per lane 4 m-contiguous elems -> 8B store.
  unsigned short* Vp = V + (size_t)blockIdx.z * 4096 * 4096;
#pragma unroll
  for (int nf = 0; nf < 4; ++nf) {
    int kpIdx = kp0 + wn * 64 + nf * 16 + (lane & 15);
    unsigned short* vr = Vp + (size_t)kpIdx * 4096 + m0 + wm * 64 + (lane >> 4) * 4;
#pragma unroll
    for (int mf = 0; mf < 4; ++mf) {
      f32x4 v = acc[mf][nf];
      ushort4 h = make_ushort4(f2bf(v[0]), f2bf(v[1]), f2bf(v[2]), f2bf(v[3]));
      *(ushort4*)(vr + mf * 16) = h;
    }
  }
}

// ---------------------------------------------------------------------------
// Stage B: per (plane, p-pair) wg, 1024 threads.
//   x = V[kp0,:] + i*V[kp0+1,:]; X=FFT(x); c_regs += H_k*X (over k)
//   y = FFT(conj(C)); out[b,l,p0]=Re y, out[b,l,p0+1]=-Im y
// ---------------------------------------------------------------------------
__global__ __launch_bounds__(1024) void conv_combine(
    const unsigned short* __restrict__ V, const float2* __restrict__ H,
    float* __restrict__ out, int bbase) {
  __shared__ float2 A[4096];
  __shared__ float2 Bb[4096];
  __shared__ float2 tw[1024];
  const int tid = threadIdx.x;
  const int p0 = blockIdx.x * 2;
  const int bout = bbase + blockIdx.y;
  const unsigned short* Vp = V + (size_t)blockIdx.y * 4096 * 4096;

  build_tw<1024>(tw, tid);
  float2 c0r = make_float2(0.f, 0.f), c1r = c0r, c2r = c0r, c3r = c0r;

  for (int k = 0; k < 16; ++k) {
    const unsigned short* v0 = Vp + (size_t)(k * 256 + p0) * 4096;
    const unsigned short* v1 = v0 + 4096;
    __syncthreads();  // prev iter / tw build done before overwriting A
    {
      int base = tid * 4;
      ushort4 a0 = *(const ushort4*)(v0 + base);
      ushort4 a1 = *(const ushort4*)(v1 + base);
      A[base + 0] = make_float2(bf2f(a0.x), bf2f(a1.x));
      A[base + 1] = make_float2(bf2f(a0.y), bf2f(a1.y));
      A[base + 2] = make_float2(bf2f(a0.z), bf2f(a1.z));
      A[base + 3] = make_float2(bf2f(a0.w), bf2f(a1.w));
    }
    __syncthreads();
    fft4096<1024>(A, Bb, tw, tid);
    const float2* Hk = H + (size_t)k * 4096;
#pragma unroll
    for (int i = 0; i < 4; ++i) {
      int f = tid + i * 1024;
      float2 x = A[f], h = Hk[f];
      float cx = h.x * x.x - h.y * x.y;
      float cy = h.x * x.y + h.y * x.x;
      if (i == 0) { c0r.x += cx; c0r.y += cy; }
      else if (i == 1) { c1r.x += cx; c1r.y += cy; }
      else if (i == 2) { c2r.x += cx; c2r.y += cy; }
      else { c3r.x += cx; c3r.y += cy; }
    }
  }
  __syncthreads();
  A[tid]        = make_float2(c0r.x, -c0r.y);
  A[tid + 1024] = make_float2(c1r.x, -c1r.y);
  A[tid + 2048] = make_float2(c2r.x, -c2r.y);
  A[tid + 3072] = make_float2(c3r.x, -c3r.y);
  __syncthreads();
  fft4096<1024>(A, Bb, tw, tid);

  float* ob = out + (size_t)bout * 4096 * 256;
#pragma unroll
  for (int i = 0; i < 4; ++i) {
    int l = tid + i * 1024;
    float2 y = A[l];
    *(float2*)(ob + (size_t)l * 256 + p0) = make_float2(y.x, -y.y);
  }
}

// ---------------------------------------------------------------------------
extern "C" void kernel_launch(void* const* d_in, const int* in_sizes, int n_in,
                              void* d_out, int out_size, void* d_ws,
                              size_t ws_size, hipStream_t stream) {
  const float* u   = (const float*)d_in[0];  // (2, 4096, 256)
  const float* ev  = (const float*)d_in[1];  // (16, 4096)
  const float* lam = (const float*)d_in[2];  // (16,)
  const float* M   = (const float*)d_in[3];  // (16, 256, 256)
  float* out = (float*)d_out;                // (2, 4096, 256)

  char* ws = (char*)d_ws;
  float2* H = (float2*)ws;                                        // 512 KB
  unsigned short* ub = (unsigned short*)(ws + (512 << 10));       // 4 MB
  unsigned short* Mt = (unsigned short*)(ws + (512 << 10) + (4 << 20));  // 2 MB
  unsigned short* V  = (unsigned short*)(ws + (512 << 10) + (6 << 20));
  const size_t fixed = (512 << 10) + (6 << 20);
  const size_t planeB = (size_t)4096 * 4096 * 2;                  // 32 MB
  const bool both = ws_size >= fixed + 2 * planeB;

  cvt_u<<<1024, 256, 0, stream>>>(u, ub);
  tr_M<<<dim3(4, 4, 16), 256, 0, stream>>>(M, Mt);
  ev_dft<<<16, 256, 0, stream>>>(ev, lam, H);

  if (both) {
    gemm_mfma<<<dim3(32, 32, 2), 256, 0, stream>>>(ub, Mt, V, 0);
    conv_combine<<<dim3(128, 2), 1024, 0, stream>>>(V, H, out, 0);
  } else {
    for (int b = 0; b < 2; ++b) {
      gemm_mfma<<<dim3(32, 32, 1), 256, 0, stream>>>(ub, Mt, V, b);
      conv_combine<<<dim3(128, 1), 1024, 0, stream>>>(V, H, out, b);
    }
  }
}

// Round 3
// 138.428 us; speedup vs baseline: 3.3153x; 1.3911x over previous
//
#include <hip/hip_runtime.h>

// B=2, L=4096, D_IN=256, D_OUT=256, K=16
// out[b,l,p] = sum_k lam_k * sum_m ev[k,(l-m)%L] * (sum_d u[b,m,d]*M[k,d,p])
//
// Frequency-domain-first pipeline (FFT commutes with the d->p projection):
//   1) Uhat[b,f,d]  = FFT_m(u[b,m,d])        (272 FFTs total, incl. ev)
//   2) Chat[b,p,f]  = sum_k H[k,f] * sum_d Uhat[b,f,d]*M[k,d,p]   (MFMA GEMM,
//      per-k complex H-apply in registers; re/im stored as split blocks)
//   3) out[b,:,p]   = IFFT_f(Chat)           (1 packed inverse FFT per p-pair)
//
// Spectrum layout (per plane), rows of Ut / cols of Chat:  [0..2047] = Re(f),
// [2048] = Nyquist (real, packed into the dead Im(0) slot), [2049..4095] = Im(f).

typedef unsigned int uint;
using u16x8 = __attribute__((ext_vector_type(8))) unsigned short;
using s16x8 = __attribute__((ext_vector_type(8))) short;
using f32x4 = __attribute__((ext_vector_type(4))) float;

__device__ __forceinline__ unsigned short f2bf(float f) {
  uint u = __float_as_uint(f);
  uint r = (u + 0x7FFF + ((u >> 16) & 1)) >> 16;   // RNE
  return (unsigned short)r;
}
__device__ __forceinline__ float bf2f(unsigned short h) {
  return __uint_as_float(((uint)h) << 16);
}

// ---------------------------------------------------------------------------
// Radix-4 Stockham DIF FFT, N=4096, 6 stages, autosort; result back in `a`.
// (verified in round 2)
// ---------------------------------------------------------------------------
template <int NT>
__device__ __forceinline__ void fft4096(float2* __restrict__ a,
                                        float2* __restrict__ b,
                                        const float2* __restrict__ tw, int tid) {
  float2* src = a;
  float2* dst = b;
#pragma unroll
  for (int s = 0; s < 12; s += 2) {
    const int m = 1 << s;
#pragma unroll
    for (int it = 0; it < 1024 / NT; ++it) {
      int idx = tid + it * NT;                 // 0..1023
      int i   = idx & (m - 1);
      int jm  = idx - i;
      float2 A0 = src[idx];
      float2 B0 = src[idx + 1024];
      float2 C0 = src[idx + 2048];
      float2 D0 = src[idx + 3072];
      float2 w1 = tw[jm];
      float2 w2 = make_float2(w1.x * w1.x - w1.y * w1.y, 2.f * w1.x * w1.y);
      float2 w3 = make_float2(w2.x * w1.x - w2.y * w1.y, w2.x * w1.y + w2.y * w1.x);
      float acx = A0.x + C0.x, acy = A0.y + C0.y;
      float amx = A0.x - C0.x, amy = A0.y - C0.y;
      float bdx = B0.x + D0.x, bdy = B0.y + D0.y;
      float bmx = B0.x - D0.x, bmy = B0.y - D0.y;
      float2 y0 = make_float2(acx + bdx, acy + bdy);
      float2 t2 = make_float2(acx - bdx, acy - bdy);
      float2 t1 = make_float2(amx + bmy, amy - bmx);
      float2 t3 = make_float2(amx - bmy, amy + bmx);
      int base = idx + 3 * jm;
      dst[base]         = y0;
      dst[base + m]     = make_float2(w1.x * t1.x - w1.y * t1.y, w1.x * t1.y + w1.y * t1.x);
      dst[base + 2 * m] = make_float2(w2.x * t2.x - w2.y * t2.y, w2.x * t2.y + w2.y * t2.x);
      dst[base + 3 * m] = make_float2(w3.x * t3.x - w3.y * t3.y, w3.x * t3.y + w3.y * t3.x);
    }
    __syncthreads();
    float2* t = src; src = dst; dst = t;
  }
}

template <int NT>
__device__ __forceinline__ void build_tw(float2* tw, int tid) {
  for (int t = tid; t < 1024; t += NT) {
    float ang = -(float)t * (6.283185307179586f / 4096.0f);
    float s, c;
    sincosf(ang, &s, &c);
    tw[t] = make_float2(c, s);
  }
}

// ---------------------------------------------------------------------------
// M[k][d][p] f32 -> Mt[k][p][d] bf16   (verified round 2)
// ---------------------------------------------------------------------------
__global__ __launch_bounds__(256) void tr_M(const float* __restrict__ M,
                                            unsigned short* __restrict__ Mt) {
  __shared__ float t[64][65];
  const int k = blockIdx.z, d0 = blockIdx.x * 64, p0 = blockIdx.y * 64;
  const int r = threadIdx.x >> 2, c0 = (threadIdx.x & 3) * 16;
  const float* src = M + ((size_t)k * 256 + d0) * 256 + p0;
#pragma unroll
  for (int j = 0; j < 4; ++j) {
    float4 v = *(const float4*)(src + (size_t)r * 256 + c0 + j * 4);
    t[r][c0 + j * 4 + 0] = v.x;
    t[r][c0 + j * 4 + 1] = v.y;
    t[r][c0 + j * 4 + 2] = v.z;
    t[r][c0 + j * 4 + 3] = v.w;
  }
  __syncthreads();
  u16x8 o0, o1;
#pragma unroll
  for (int j = 0; j < 8; ++j) o0[j] = f2bf(t[c0 + j][r]);
#pragma unroll
  for (int j = 0; j < 8; ++j) o1[j] = f2bf(t[c0 + 8 + j][r]);
  unsigned short* dst = Mt + ((size_t)k * 256 + p0 + r) * 256 + d0 + c0;
  *(u16x8*)dst = o0;
  *(u16x8*)(dst + 8) = o1;
}

// ---------------------------------------------------------------------------
// Forward FFTs. bid<256: u d-pair FFT -> Ut (bf16). bid>=256: ev FFT -> Hbuf.
// Ut[plane][f2][d]: f2 in [0,2048) = Re U[f]; f2==2048 row: Nyquist (real);
// f2 in (2048,4096) = Im U[f2-2048].  Hbuf[k][f2] same convention (f32).
// ---------------------------------------------------------------------------
__global__ __launch_bounds__(1024) void fft_fwd(const float* __restrict__ u,
                                                const float* __restrict__ ev,
                                                const float* __restrict__ lam,
                                                unsigned short* __restrict__ Ut,
                                                float* __restrict__ Hbuf) {
  __shared__ float2 A[4096];
  __shared__ float2 Bb[4096];
  __shared__ float2 tw[1024];
  const int tid = threadIdx.x;
  const int bid = blockIdx.x;
  build_tw<1024>(tw, tid);

  if (bid < 256) {
    const int plane = bid >> 7, pair = bid & 127;
    const int d0 = pair * 2;
    const float* ub = u + (size_t)plane * 4096 * 256 + d0;
#pragma unroll
    for (int i = 0; i < 4; ++i) {
      int l = tid + i * 1024;
      A[l] = *(const float2*)(ub + (size_t)l * 256);   // (u[l,d0], u[l,d0+1])
    }
    __syncthreads();
    fft4096<1024>(A, Bb, tw, tid);
    unsigned short* Up = Ut + (size_t)plane * 4096 * 256 + d0;
#pragma unroll
    for (int i = 0; i < 2; ++i) {
      int f = tid + i * 1024;                          // 0..2047
      float u0x, u0y, u1x, u1y;
      if (f == 0) {
        float2 X0 = A[0], Xn = A[2048];
        u0x = X0.x; u1x = X0.y;                        // DC (real)
        u0y = Xn.x; u1y = Xn.y;                        // Nyquist (real) -> im-slot 0
      } else {
        float2 Xa = A[f], Xb = A[4096 - f];
        u0x = 0.5f * (Xa.x + Xb.x);
        u0y = 0.5f * (Xa.y - Xb.y);
        u1x = 0.5f * (Xa.y + Xb.y);
        u1y = 0.5f * (Xb.x - Xa.x);
      }
      ushort2 re = make_ushort2(f2bf(u0x), f2bf(u1x));
      ushort2 im = make_ushort2(f2bf(u0y), f2bf(u1y));
      *(ushort2*)(Up + (size_t)f * 256)          = re;
      *(ushort2*)(Up + (size_t)(2048 + f) * 256) = im;
    }
  } else {
    const int k = bid - 256;
    const float* eb = ev + (size_t)k * 4096;
#pragma unroll
    for (int i = 0; i < 4; ++i) {
      int l = tid + i * 1024;
      A[l] = make_float2(eb[l], 0.0f);
    }
    __syncthreads();
    fft4096<1024>(A, Bb, tw, tid);
    const float sc = lam[k] * (1.0f / 4096.0f);
    float* Hp = Hbuf + (size_t)k * 4096;
#pragma unroll
    for (int i = 0; i < 2; ++i) {
      int f = tid + i * 1024;
      float2 X = A[f];
      Hp[f] = sc * X.x;
      Hp[2048 + f] = (f == 0) ? sc * A[2048].x : sc * X.y;   // im; slot0=Nyquist
    }
  }
}

// ---------------------------------------------------------------------------
// Spectral GEMM + per-k complex filter accumulate.
// Tile: 64 p-rows x 64 f-bins (128 cols: 64 re + 64 im).  4 waves, wave w owns
// bins [fb+16w, fb+16w+16): frags 4(p) x {re,im}; per k: 64 MFMA then H-apply.
// LDS: Us[128][256] bf16 (64KB, staged once) + Ms[64][256] (32KB, per k).
// 16B-chunk XOR swizzle (c ^= row&7) for conflict-free ds_read_b128.
// ---------------------------------------------------------------------------
__global__ __launch_bounds__(256) void gemm_spec(const unsigned short* __restrict__ Ut,
                                                 const unsigned short* __restrict__ Mt,
                                                 const float* __restrict__ Hbuf,
                                                 float* __restrict__ Chat) {
  __shared__ unsigned short Us[128 * 256];
  __shared__ unsigned short Ms[64 * 256];
  const int p0    = blockIdx.x * 64;
  const int fb    = blockIdx.y * 64;
  const int plane = blockIdx.z;
  const int tid  = threadIdx.x;
  const int lane = tid & 63;
  const int wave = tid >> 6;

  // stage U columns for this f-tile (re rows then im rows)
  const unsigned short* Up = Ut + (size_t)plane * 4096 * 256;
#pragma unroll
  for (int it = 0; it < 16; ++it) {
    int cl = tid + it * 256;
    int r = cl >> 5, c = cl & 31;
    int f2 = (r < 64) ? (fb + r) : (2048 + fb + (r - 64));
    u16x8 v = *(const u16x8*)(Up + (size_t)f2 * 256 + c * 8);
    *(u16x8*)(&Us[r * 256 + ((c ^ (r & 7)) * 8)]) = v;
  }

  // prefetch M(k=0) into regs
  u16x8 mreg[8];
#pragma unroll
  for (int it = 0; it < 8; ++it) {
    int cl = tid + it * 256;
    int r = cl >> 5, c = cl & 31;
    mreg[it] = *(const u16x8*)(Mt + (size_t)(p0 + r) * 256 + c * 8);
  }

  f32x4 cre[4], cim[4];
#pragma unroll
  for (int m = 0; m < 4; ++m) {
    cre[m] = (f32x4){0.f, 0.f, 0.f, 0.f};
    cim[m] = (f32x4){0.f, 0.f, 0.f, 0.f};
  }

  const int bin = fb + wave * 16 + (lane & 15);     // this lane's f-bin
  const int rb_re = wave * 16 + (lane & 15);        // Us row for re frag
  const int rb_im = 64 + rb_re;                     // Us row for im frag

  for (int k = 0; k < 16; ++k) {
    if (k > 0) __syncthreads();                     // prev compute done with Ms
#pragma unroll
    for (int it = 0; it < 8; ++it) {
      int cl = tid + it * 256;
      int r = cl >> 5, c = cl & 31;
      *(u16x8*)(&Ms[r * 256 + ((c ^ (r & 7)) * 8)]) = mreg[it];
    }
    if (k < 15) {
      const unsigned short* Mk = Mt + (size_t)(k + 1) * 65536;
#pragma unroll
      for (int it = 0; it < 8; ++it) {
        int cl = tid + it * 256;
        int r = cl >> 5, c = cl & 31;
        mreg[it] = *(const u16x8*)(Mk + (size_t)(p0 + r) * 256 + c * 8);
      }
    }
    __syncthreads();                                // Ms (and, k=0, Us) ready

    f32x4 are[4], aim[4];
#pragma unroll
    for (int m = 0; m < 4; ++m) {
      are[m] = (f32x4){0.f, 0.f, 0.f, 0.f};
      aim[m] = (f32x4){0.f, 0.f, 0.f, 0.f};
    }
#pragma unroll
    for (int kk = 0; kk < 8; ++kk) {
      const int kc = kk * 4 + (lane >> 4);
      s16x8 bre = *(const s16x8*)(&Us[rb_re * 256 + ((kc ^ (rb_re & 7)) * 8)]);
      s16x8 bim = *(const s16x8*)(&Us[rb_im * 256 + ((kc ^ (rb_im & 7)) * 8)]);
#pragma unroll
      for (int m = 0; m < 4; ++m) {
        int row = m * 16 + (lane & 15);
        s16x8 af = *(const s16x8*)(&Ms[row * 256 + ((kc ^ (row & 7)) * 8)]);
        are[m] = __builtin_amdgcn_mfma_f32_16x16x32_bf16(af, bre, are[m], 0, 0, 0);
        aim[m] = __builtin_amdgcn_mfma_f32_16x16x32_bf16(af, bim, aim[m], 0, 0, 0);
      }
    }
    // complex H-apply (lane-local): C += H_k * V
    float hre = Hbuf[(size_t)k * 4096 + bin];
    float hs  = Hbuf[(size_t)k * 4096 + 2048 + bin];
    bool sp = (bin == 0);                 // im slot holds Nyquist at bin 0
    float him = sp ? 0.0f : hs;
    float hA  = sp ? hs : hre;            // multiplies Vim in Cim update
#pragma unroll
    for (int m = 0; m < 4; ++m)
#pragma unroll
      for (int i = 0; i < 4; ++i) {
        cre[m][i] += hre * are[m][i] - him * aim[m][i];
        cim[m][i] += hA * aim[m][i] + him * are[m][i];
      }
  }

  // store: Chat[plane][p][0..2047]=re, [2048..4095]=im (slot 2048 = Nyquist)
  float* Cp = Chat + ((size_t)plane * 256 + p0) * 4096;
#pragma unroll
  for (int m = 0; m < 4; ++m)
#pragma unroll
    for (int i = 0; i < 4; ++i) {
      int pl = m * 16 + (lane >> 4) * 4 + i;
      Cp[(size_t)pl * 4096 + bin]        = cre[m][i];
      Cp[(size_t)pl * 4096 + 2048 + bin] = cim[m][i];
    }
}

// ---------------------------------------------------------------------------
// Inverse: per (plane, p-pair): rebuild Hermitian spectra, pack p0+i*p1,
// y = conj(FFT(conj(Z))) -> out0 = Re, out1 = -Im  (scale already in H).
// ---------------------------------------------------------------------------
__global__ __launch_bounds__(1024) void ifft_store(const float* __restrict__ Chat,
                                                   float* __restrict__ out) {
  __shared__ float2 A[4096];
  __shared__ float2 Bb[4096];
  __shared__ float2 tw[1024];
  const int tid = threadIdx.x;
  const int p0 = blockIdx.x * 2;
  const int plane = blockIdx.y;
  const float* C0 = Chat + ((size_t)plane * 256 + p0) * 4096;
  const float* C1 = C0 + 4096;
  build_tw<1024>(tw, tid);

  if (tid == 0) {
    A[0]    = make_float2(C0[0], -C1[0]);          // DC (real)
    A[2048] = make_float2(C0[2048], -C1[2048]);    // Nyquist (real)
  } else {
    int f = tid;                                   // 1..1023
    float cr0 = C0[f], ci0 = C0[2048 + f];
    float cr1 = C1[f], ci1 = C1[2048 + f];
    A[f]        = make_float2(cr0 - ci1, -(ci0 + cr1));
    A[4096 - f] = make_float2(cr0 + ci1, ci0 - cr1);
  }
  {
    int f = tid + 1024;                            // 1024..2047
    float cr0 = C0[f], ci0 = C0[2048 + f];
    float cr1 = C1[f], ci1 = C1[2048 + f];
    A[f]        = make_float2(cr0 - ci1, -(ci0 + cr1));
    A[4096 - f] = make_float2(cr0 + ci1, ci0 - cr1);
  }
  __syncthreads();
  fft4096<1024>(A, Bb, tw, tid);

  float* ob = out + (size_t)plane * 4096 * 256 + p0;
#pragma unroll
  for (int i = 0; i < 4; ++i) {
    int l = tid + i * 1024;
    float2 g = A[l];
    *(float2*)(ob + (size_t)l * 256) = make_float2(g.x, -g.y);
  }
}

// ---------------------------------------------------------------------------
extern "C" void kernel_launch(void* const* d_in, const int* in_sizes, int n_in,
                              void* d_out, int out_size, void* d_ws,
                              size_t ws_size, hipStream_t stream) {
  const float* u   = (const float*)d_in[0];  // (2, 4096, 256)
  const float* ev  = (const float*)d_in[1];  // (16, 4096)
  const float* lam = (const float*)d_in[2];  // (16,)
  const float* M   = (const float*)d_in[3];  // (16, 256, 256)
  float* out = (float*)d_out;                // (2, 4096, 256)

  char* ws = (char*)d_ws;
  float* Hbuf        = (float*)ws;                                  // 256 KB
  unsigned short* Mt = (unsigned short*)(ws + (256 << 10));         // 2 MB
  unsigned short* Ut = (unsigned short*)(ws + (256 << 10) + (2 << 20));  // 4 MB
  float* Chat        = (float*)(ws + (256 << 10) + (6 << 20));      // 8 MB

  tr_M<<<dim3(4, 4, 16), 256, 0, stream>>>(M, Mt);
  fft_fwd<<<272, 1024, 0, stream>>>(u, ev, lam, Ut, Hbuf);
  gemm_spec<<<dim3(4, 32, 2), 256, 0, stream>>>(Ut, Mt, Hbuf, Chat);
  ifft_store<<<dim3(128, 2), 1024, 0, stream>>>(Chat, out);
}

// Round 8
// 120.706 us; speedup vs baseline: 3.8020x; 1.1468x over previous
//
#include <hip/hip_runtime.h>

// B=2, L=4096, D_IN=256, D_OUT=256, K=16
// out[b,l,p] = sum_k lam_k * sum_m ev[k,(l-m)%L] * (sum_d u[b,m,d]*M[k,d,p])
//
// Frequency-domain-first pipeline:
//   0) ubT[b,d,l] = bf16 transpose of u;  Mt[k,p,d] = bf16 transpose of M
//   1) Uhat[b,f2,d] = FFT_l(ubT)   (256 packed d-pair FFTs + 16 ev FFTs)
//   2) Chat[b,p,f2] = sum_k H[k,f] * sum_d Uhat[f,d]*Mt[k,p,d]   (MFMA,
//      512-thr blocks, k split across wave-halves, LDS reduction)
//   3) ytmp[b,p,l] = IFFT_f(Chat);  4) out[b,l,p] = transpose(ytmp)
//
// Spectrum rows f2: [0..2047]=Re(f), [2048]=Nyquist(real, in dead Im(0)),
// [2049..4095]=Im(f).   (verified rounds 2-3, absmax 4.0)

typedef unsigned int uint;
using u16x8 = __attribute__((ext_vector_type(8))) unsigned short;
using s16x8 = __attribute__((ext_vector_type(8))) short;
using f32x4 = __attribute__((ext_vector_type(4))) float;

__device__ __forceinline__ unsigned short f2bf(float f) {
  uint u = __float_as_uint(f);
  uint r = (u + 0x7FFF + ((u >> 16) & 1)) >> 16;   // RNE
  return (unsigned short)r;
}
__device__ __forceinline__ float bf2f(unsigned short h) {
  return __uint_as_float(((uint)h) << 16);
}

// ---------------------------------------------------------------------------
// Radix-4 Stockham DIF FFT, N=4096, 6 stages, autosort (verified r2/r3).
// ---------------------------------------------------------------------------
template <int NT>
__device__ __forceinline__ void fft4096(float2* __restrict__ a,
                                        float2* __restrict__ b,
                                        const float2* __restrict__ tw, int tid) {
  float2* src = a;
  float2* dst = b;
#pragma unroll
  for (int s = 0; s < 12; s += 2) {
    const int m = 1 << s;
#pragma unroll
    for (int it = 0; it < 1024 / NT; ++it) {
      int idx = tid + it * NT;
      int i   = idx & (m - 1);
      int jm  = idx - i;
      float2 A0 = src[idx];
      float2 B0 = src[idx + 1024];
      float2 C0 = src[idx + 2048];
      float2 D0 = src[idx + 3072];
      float2 w1 = tw[jm];
      float2 w2 = make_float2(w1.x * w1.x - w1.y * w1.y, 2.f * w1.x * w1.y);
      float2 w3 = make_float2(w2.x * w1.x - w2.y * w1.y, w2.x * w1.y + w2.y * w1.x);
      float acx = A0.x + C0.x, acy = A0.y + C0.y;
      float amx = A0.x - C0.x, amy = A0.y - C0.y;
      float bdx = B0.x + D0.x, bdy = B0.y + D0.y;
      float bmx = B0.x - D0.x, bmy = B0.y - D0.y;
      float2 y0 = make_float2(acx + bdx, acy + bdy);
      float2 t2 = make_float2(acx - bdx, acy - bdy);
      float2 t1 = make_float2(amx + bmy, amy - bmx);
      float2 t3 = make_float2(amx - bmy, amy + bmx);
      int base = idx + 3 * jm;
      dst[base]         = y0;
      dst[base + m]     = make_float2(w1.x * t1.x - w1.y * t1.y, w1.x * t1.y + w1.y * t1.x);
      dst[base + 2 * m] = make_float2(w2.x * t2.x - w2.y * t2.y, w2.x * t2.y + w2.y * t2.x);
      dst[base + 3 * m] = make_float2(w3.x * t3.x - w3.y * t3.y, w3.x * t3.y + w3.y * t3.x);
    }
    __syncthreads();
    float2* t = src; src = dst; dst = t;
  }
}

template <int NT>
__device__ __forceinline__ void build_tw(float2* tw, int tid) {
  for (int t = tid; t < 1024; t += NT) {
    float ang = -(float)t * (6.283185307179586f / 4096.0f);
    float s, c;
    sincosf(ang, &s, &c);
    tw[t] = make_float2(c, s);
  }
}

// ---------------------------------------------------------------------------
// M[k][d][p] f32 -> Mt[k][p][d] bf16   (verified r2/r3)
// ---------------------------------------------------------------------------
__global__ __launch_bounds__(256) void tr_M(const float* __restrict__ M,
                                            unsigned short* __restrict__ Mt) {
  __shared__ float t[64][65];
  const int k = blockIdx.z, d0 = blockIdx.x * 64, p0 = blockIdx.y * 64;
  const int r = threadIdx.x >> 2, c0 = (threadIdx.x & 3) * 16;
  const float* src = M + ((size_t)k * 256 + d0) * 256 + p0;
#pragma unroll
  for (int j = 0; j < 4; ++j) {
    float4 v = *(const float4*)(src + (size_t)r * 256 + c0 + j * 4);
    t[r][c0 + j * 4 + 0] = v.x;
    t[r][c0 + j * 4 + 1] = v.y;
    t[r][c0 + j * 4 + 2] = v.z;
    t[r][c0 + j * 4 + 3] = v.w;
  }
  __syncthreads();
  u16x8 o0, o1;
#pragma unroll
  for (int j = 0; j < 8; ++j) o0[j] = f2bf(t[c0 + j][r]);
#pragma unroll
  for (int j = 0; j < 8; ++j) o1[j] = f2bf(t[c0 + 8 + j][r]);
  unsigned short* dst = Mt + ((size_t)k * 256 + p0 + r) * 256 + d0 + c0;
  *(u16x8*)dst = o0;
  *(u16x8*)(dst + 8) = o1;
}

// ---------------------------------------------------------------------------
// u[b][l][d] f32 -> ubT[b][d][l] bf16  (64x64 tiles, coalesced both sides)
// ---------------------------------------------------------------------------
__global__ __launch_bounds__(256) void tr_u(const float* __restrict__ u,
                                            unsigned short* __restrict__ ubT) {
  __shared__ float t[64][65];
  const int l0 = blockIdx.x * 64, d0 = blockIdx.y * 64, plane = blockIdx.z;
  const int r = threadIdx.x >> 2, c0 = (threadIdx.x & 3) * 16;
  const float* src = u + ((size_t)plane * 4096 + l0) * 256 + d0;
#pragma unroll
  for (int j = 0; j < 4; ++j) {
    float4 v = *(const float4*)(src + (size_t)r * 256 + c0 + j * 4);
    t[r][c0 + j * 4 + 0] = v.x;
    t[r][c0 + j * 4 + 1] = v.y;
    t[r][c0 + j * 4 + 2] = v.z;
    t[r][c0 + j * 4 + 3] = v.w;
  }
  __syncthreads();
  u16x8 o0, o1;
#pragma unroll
  for (int j = 0; j < 8; ++j) o0[j] = f2bf(t[c0 + j][r]);
#pragma unroll
  for (int j = 0; j < 8; ++j) o1[j] = f2bf(t[c0 + 8 + j][r]);
  unsigned short* dst = ubT + ((size_t)plane * 256 + d0 + r) * 4096 + l0 + c0;
  *(u16x8*)dst = o0;
  *(u16x8*)(dst + 8) = o1;
}

// ---------------------------------------------------------------------------
// Forward FFTs. bid<256: u d-pair (XCD-grouped so each Ut 64B line is written
// by one XCD). bid>=256: ev -> Hbuf.
// ---------------------------------------------------------------------------
__global__ __launch_bounds__(1024) void fft_fwd(const unsigned short* __restrict__ ubT,
                                                const float* __restrict__ ev,
                                                const float* __restrict__ lam,
                                                unsigned short* __restrict__ Ut,
                                                float* __restrict__ Hbuf) {
  __shared__ float2 A[4096];
  __shared__ float2 Bb[4096];
  __shared__ float2 tw[1024];
  const int tid = threadIdx.x;
  const int bid = blockIdx.x;
  build_tw<1024>(tw, tid);

  if (bid < 256) {
    const int plane = bid >> 7;
    const int jj = bid & 127;
    const int pair = (jj & 7) * 16 + (jj >> 3);   // XCD x -> pairs 16x..16x+15
    const int d0 = pair * 2;
    const unsigned short* r0 = ubT + ((size_t)plane * 256 + d0) * 4096;
    const unsigned short* r1 = r0 + 4096;
    const int l0 = tid * 4;
    ushort4 a4 = *(const ushort4*)(r0 + l0);
    ushort4 b4 = *(const ushort4*)(r1 + l0);
    A[l0 + 0] = make_float2(bf2f(a4.x), bf2f(b4.x));
    A[l0 + 1] = make_float2(bf2f(a4.y), bf2f(b4.y));
    A[l0 + 2] = make_float2(bf2f(a4.z), bf2f(b4.z));
    A[l0 + 3] = make_float2(bf2f(a4.w), bf2f(b4.w));
    __syncthreads();
    fft4096<1024>(A, Bb, tw, tid);
    unsigned short* Up = Ut + (size_t)plane * 4096 * 256 + d0;
#pragma unroll
    for (int i = 0; i < 2; ++i) {
      int f = tid + i * 1024;                     // 0..2047
      float u0x, u0y, u1x, u1y;
      if (f == 0) {
        float2 X0 = A[0], Xn = A[2048];
        u0x = X0.x; u1x = X0.y;                   // DC (real)
        u0y = Xn.x; u1y = Xn.y;                   // Nyquist -> im-slot 0
      } else {
        float2 Xa = A[f], Xb = A[4096 - f];
        u0x = 0.5f * (Xa.x + Xb.x);
        u0y = 0.5f * (Xa.y - Xb.y);
        u1x = 0.5f * (Xa.y + Xb.y);
        u1y = 0.5f * (Xb.x - Xa.x);
      }
      ushort2 re = make_ushort2(f2bf(u0x), f2bf(u1x));
      ushort2 im = make_ushort2(f2bf(u0y), f2bf(u1y));
      *(ushort2*)(Up + (size_t)f * 256)          = re;
      *(ushort2*)(Up + (size_t)(2048 + f) * 256) = im;
    }
  } else {
    const int k = bid - 256;
    const float* eb = ev + (size_t)k * 4096;
#pragma unroll
    for (int i = 0; i < 4; ++i) {
      int l = tid + i * 1024;
      A[l] = make_float2(eb[l], 0.0f);
    }
    __syncthreads();
    fft4096<1024>(A, Bb, tw, tid);
    const float sc = lam[k] * (1.0f / 4096.0f);
    float* Hp = Hbuf + (size_t)k * 4096;
#pragma unroll
    for (int i = 0; i < 2; ++i) {
      int f = tid + i * 1024;
      float2 X = A[f];
      Hp[f] = sc * X.x;
      Hp[2048 + f] = (f == 0) ? sc * A[2048].x : sc * X.y;
    }
  }
}

// ---------------------------------------------------------------------------
// Spectral GEMM + per-k complex filter accumulate.  512 threads, 8 waves.
// Waves 0-3: k=0..7 into Ms[0]; waves 4-7: k=8..15 into Ms[1].
// Tile 64 p x 64 bins; wave (w&3) owns 16 bins (re+im fragments).
// End: LDS reduction of the two k-halves, waves 0-3 store Chat.
// LDS: Us 64K + Ms 2x32K + Hlds 8K = 136K -> 1 block/CU, 2 waves/SIMD.
// ---------------------------------------------------------------------------
__global__ __launch_bounds__(512) void gemm_spec(const unsigned short* __restrict__ Ut,
                                                 const unsigned short* __restrict__ Mt,
                                                 const float* __restrict__ Hbuf,
                                                 float* __restrict__ Chat) {
  __shared__ unsigned short Us[128 * 256];
  __shared__ unsigned short Ms[2][64 * 256];
  __shared__ float Hlds[16 * 128];
  // XCD-swizzled decode: each XCD gets 4 consecutive f-tiles x all p,plane
  const int gi  = blockIdx.x;
  const int xcd = gi & 7;
  const int gj  = gi >> 3;                  // 0..31
  const int fb    = (xcd * 4 + (gj & 3)) * 64;
  const int p0    = ((gj >> 2) & 3) * 64;
  const int plane = gj >> 4;

  const int tid  = threadIdx.x;
  const int lane = tid & 63;
  const int wave = tid >> 6;
  const int half = wave >> 2;               // k-half
  const int w4   = wave & 3;                // bin-group
  const int th   = tid & 255;

  // stage U columns for this f-tile (re rows then im rows)
  const unsigned short* Up = Ut + (size_t)plane * 4096 * 256;
#pragma unroll
  for (int it = 0; it < 8; ++it) {
    int cl = tid + it * 512;
    int r = cl >> 5, c = cl & 31;
    int f2 = (r < 64) ? (fb + r) : (2048 + fb + (r - 64));
    u16x8 v = *(const u16x8*)(Up + (size_t)f2 * 256 + c * 8);
    *(u16x8*)(&Us[r * 256 + ((c ^ (r & 7)) * 8)]) = v;
  }
  // stage H for this f-tile: Hlds[k*128 + part*64 + j]
#pragma unroll
  for (int it = 0; it < 4; ++it) {
    int i2 = tid + it * 512;
    int k = i2 >> 7, rem = i2 & 127;
    Hlds[i2] = Hbuf[(size_t)k * 4096 + (rem >> 6) * 2048 + fb + (rem & 63)];
  }

  // prefetch M for this half's first k
  const unsigned short* Mbase = Mt + (size_t)half * 8 * 65536;
  u16x8 mreg[8];
#pragma unroll
  for (int it = 0; it < 8; ++it) {
    int cl = th + it * 256;
    int r = cl >> 5, c = cl & 31;
    mreg[it] = *(const u16x8*)(Mbase + (size_t)(p0 + r) * 256 + c * 8);
  }

  f32x4 cre[4], cim[4];
#pragma unroll
  for (int m = 0; m < 4; ++m) {
    cre[m] = (f32x4){0.f, 0.f, 0.f, 0.f};
    cim[m] = (f32x4){0.f, 0.f, 0.f, 0.f};
  }

  const int binoff = w4 * 16 + (lane & 15);
  const int bin = fb + binoff;
  const int rb_re = binoff;
  const int rb_im = 64 + binoff;

  for (int kh = 0; kh < 8; ++kh) {
    if (kh > 0) __syncthreads();            // prev compute done with Ms
#pragma unroll
    for (int it = 0; it < 8; ++it) {
      int cl = th + it * 256;
      int r = cl >> 5, c = cl & 31;
      *(u16x8*)(&Ms[half][r * 256 + ((c ^ (r & 7)) * 8)]) = mreg[it];
    }
    if (kh < 7) {
      const unsigned short* Mk = Mbase + (size_t)(kh + 1) * 65536;
#pragma unroll
      for (int it = 0; it < 8; ++it) {
        int cl = th + it * 256;
        int r = cl >> 5, c = cl & 31;
        mreg[it] = *(const u16x8*)(Mk + (size_t)(p0 + r) * 256 + c * 8);
      }
    }
    __syncthreads();                        // Ms (and Us/Hlds at kh=0) ready

    f32x4 are[4], aim[4];
#pragma unroll
    for (int m = 0; m < 4; ++m) {
      are[m] = (f32x4){0.f, 0.f, 0.f, 0.f};
      aim[m] = (f32x4){0.f, 0.f, 0.f, 0.f};
    }
#pragma unroll
    for (int kk = 0; kk < 8; ++kk) {
      const int kc = kk * 4 + (lane >> 4);
      s16x8 bre = *(const s16x8*)(&Us[rb_re * 256 + ((kc ^ (rb_re & 7)) * 8)]);
      s16x8 bim = *(const s16x8*)(&Us[rb_im * 256 + ((kc ^ (rb_im & 7)) * 8)]);
#pragma unroll
      for (int m = 0; m < 4; ++m) {
        int row = m * 16 + (lane & 15);
        s16x8 af = *(const s16x8*)(&Ms[half][row * 256 + ((kc ^ (row & 7)) * 8)]);
        are[m] = __builtin_amdgcn_mfma_f32_16x16x32_bf16(af, bre, are[m], 0, 0, 0);
        aim[m] = __builtin_amdgcn_mfma_f32_16x16x32_bf16(af, bim, aim[m], 0, 0, 0);
      }
    }
    const int k = kh + 8 * half;
    float hre = Hlds[k * 128 + binoff];
    float hs  = Hlds[k * 128 + 64 + binoff];
    bool sp = (bin == 0);                   // im slot holds Nyquist at bin 0
    float him = sp ? 0.0f : hs;
    float hA  = sp ? hs : hre;
#pragma unroll
    for (int m = 0; m < 4; ++m)
#pragma unroll
      for (int i = 0; i < 4; ++i) {
        cre[m][i] += hre * are[m][i] - him * aim[m][i];
        cim[m][i] += hA * aim[m][i] + him * are[m][i];
      }
  }

  // reduce the two k-halves via LDS (reuse Us as 64KB float scratch)
  __syncthreads();
  float* Red = (float*)Us;
#pragma unroll
  for (int m = 0; m < 4; ++m)
#pragma unroll
    for (int i = 0; i < 4; ++i) {
      Red[(m * 4 + i) * 512 + tid]        = cre[m][i];
      Red[(16 + m * 4 + i) * 512 + tid]   = cim[m][i];
    }
  __syncthreads();
  if (tid < 256) {
#pragma unroll
    for (int m = 0; m < 4; ++m)
#pragma unroll
      for (int i = 0; i < 4; ++i) {
        cre[m][i] += Red[(m * 4 + i) * 512 + tid + 256];
        cim[m][i] += Red[(16 + m * 4 + i) * 512 + tid + 256];
      }
    float* Cp = Chat + ((size_t)plane * 256 + p0) * 4096;
#pragma unroll
    for (int m = 0; m < 4; ++m)
#pragma unroll
      for (int i = 0; i < 4; ++i) {
        int pl = m * 16 + (lane >> 4) * 4 + i;
        Cp[(size_t)pl * 4096 + bin]        = cre[m][i];
        Cp[(size_t)pl * 4096 + 2048 + bin] = cim[m][i];
      }
  }
}

// ---------------------------------------------------------------------------
// Inverse: rebuild Hermitian spectra per p-pair, y = FFT(conj(C));
// write ytmp[plane][p][l] CONTIGUOUSLY (transpose to out happens after).
// ---------------------------------------------------------------------------
__global__ __launch_bounds__(1024) void ifft_store(const float* __restrict__ Chat,
                                                   float* __restrict__ ytmp) {
  __shared__ float2 A[4096];
  __shared__ float2 Bb[4096];
  __shared__ float2 tw[1024];
  const int tid = threadIdx.x;
  const int p0 = blockIdx.x * 2;
  const int plane = blockIdx.y;
  const float* C0 = Chat + ((size_t)plane * 256 + p0) * 4096;
  const float* C1 = C0 + 4096;
  build_tw<1024>(tw, tid);

  if (tid == 0) {
    A[0]    = make_float2(C0[0], -C1[0]);          // DC (real)
    A[2048] = make_float2(C0[2048], -C1[2048]);    // Nyquist (real)
  } else {
    int f = tid;                                   // 1..1023
    float cr0 = C0[f], ci0 = C0[2048 + f];
    float cr1 = C1[f], ci1 = C1[2048 + f];
    A[f]        = make_float2(cr0 - ci1, -(ci0 + cr1));
    A[4096 - f] = make_float2(cr0 + ci1, ci0 - cr1);
  }
  {
    int f = tid + 1024;                            // 1024..2047
    float cr0 = C0[f], ci0 = C0[2048 + f];
    float cr1 = C1[f], ci1 = C1[2048 + f];
    A[f]        = make_float2(cr0 - ci1, -(ci0 + cr1));
    A[4096 - f] = make_float2(cr0 + ci1, ci0 - cr1);
  }
  __syncthreads();
  fft4096<1024>(A, Bb, tw, tid);

  float* y0 = ytmp + ((size_t)plane * 256 + p0) * 4096;
  float* y1 = y0 + 4096;
#pragma unroll
  for (int i = 0; i < 4; ++i) {
    int l = tid + i * 1024;
    float2 g = A[l];
    y0[l] = g.x;
    y1[l] = -g.y;
  }
}

// ---------------------------------------------------------------------------
// ytmp[plane][p][l] -> out[plane][l][p]   (64x64 f32 tiles, coalesced)
// ---------------------------------------------------------------------------
__global__ __launch_bounds__(256) void tr_out(const float* __restrict__ ytmp,
                                              float* __restrict__ out) {
  __shared__ float t[64][65];
  const int l0 = blockIdx.x * 64, p0 = blockIdx.y * 64, plane = blockIdx.z;
  const int r = threadIdx.x >> 2, c0 = (threadIdx.x & 3) * 16;
  const float* src = ytmp + ((size_t)plane * 256 + p0 + r) * 4096 + l0;
#pragma unroll
  for (int j = 0; j < 4; ++j) {
    float4 v = *(const float4*)(src + c0 + j * 4);
    t[r][c0 + j * 4 + 0] = v.x;
    t[r][c0 + j * 4 + 1] = v.y;
    t[r][c0 + j * 4 + 2] = v.z;
    t[r][c0 + j * 4 + 3] = v.w;
  }
  __syncthreads();
  float* dst = out + ((size_t)plane * 4096 + l0 + r) * 256 + p0 + c0;
#pragma unroll
  for (int q = 0; q < 4; ++q) {
    float4 o;
    o.x = t[c0 + q * 4 + 0][r];
    o.y = t[c0 + q * 4 + 1][r];
    o.z = t[c0 + q * 4 + 2][r];
    o.w = t[c0 + q * 4 + 3][r];
    *(float4*)(dst + q * 4) = o;
  }
}

// ---------------------------------------------------------------------------
extern "C" void kernel_launch(void* const* d_in, const int* in_sizes, int n_in,
                              void* d_out, int out_size, void* d_ws,
                              size_t ws_size, hipStream_t stream) {
  const float* u   = (const float*)d_in[0];  // (2, 4096, 256)
  const float* ev  = (const float*)d_in[1];  // (16, 4096)
  const float* lam = (const float*)d_in[2];  // (16,)
  const float* M   = (const float*)d_in[3];  // (16, 256, 256)
  float* out = (float*)d_out;                // (2, 4096, 256)

  char* ws = (char*)d_ws;
  float* Hbuf         = (float*)ws;                          // 256 KB
  unsigned short* Mt  = (unsigned short*)(ws + (256 << 10)); // 2 MB
  unsigned short* ubT = (unsigned short*)(ws + (256 << 10) + (2 << 20));  // 4 MB
  unsigned short* Ut  = (unsigned short*)(ws + (256 << 10) + (6 << 20));  // 4 MB
  float* Chat         = (float*)(ws + (256 << 10) + (10 << 20));          // 8 MB
  float* ytmp         = (float*)(ws + (256 << 10) + (18 << 20));          // 8 MB

  tr_M<<<dim3(4, 4, 16), 256, 0, stream>>>(M, Mt);
  tr_u<<<dim3(64, 4, 2), 256, 0, stream>>>(u, ubT);
  fft_fwd<<<272, 1024, 0, stream>>>(ubT, ev, lam, Ut, Hbuf);
  gemm_spec<<<256, 512, 0, stream>>>(Ut, Mt, Hbuf, Chat);
  ifft_store<<<dim3(128, 2), 1024, 0, stream>>>(Chat, ytmp);
  tr_out<<<dim3(64, 4, 2), 256, 0, stream>>>(ytmp, out);
}

// Round 9
// 117.480 us; speedup vs baseline: 3.9064x; 1.0275x over previous
//
#include <hip/hip_runtime.h>

// B=2, L=4096, D_IN=256, D_OUT=256, K=16
// out[b,l,p] = sum_k lam_k * sum_m ev[k,(l-m)%L] * (sum_d u[b,m,d]*M[k,d,p])
//
// Frequency-domain-first pipeline:
//   0) prep: ubT[b,d,l] = bf16 transpose of u;  Mt[k,p,d] = bf16 transpose of M
//   1) Uhat[b,f2,d] = FFT_l(ubT)   (256 packed d-pair FFTs + 16 ev FFTs)
//   2) Chat[b,p,f2] = sum_k H[k,f] * sum_d Uhat[f,d]*Mt[k,p,d]   (MFMA,
//      512-thr blocks, k split across wave-halves; U-fragments held in
//      REGISTERS across the k-loop (k-independent); LDS reduction at end)
//   3) ytmp[b,p,l] = IFFT_f(Chat);  4) out[b,l,p] = transpose(ytmp)
//
// Spectrum rows f2: [0..2047]=Re(f), [2048]=Nyquist(real, in dead Im(0)),
// [2049..4095]=Im(f).   (verified rounds 2-3/8, absmax 4.0)

typedef unsigned int uint;
using u16x8 = __attribute__((ext_vector_type(8))) unsigned short;
using s16x8 = __attribute__((ext_vector_type(8))) short;
using f32x4 = __attribute__((ext_vector_type(4))) float;

__device__ __forceinline__ unsigned short f2bf(float f) {
  uint u = __float_as_uint(f);
  uint r = (u + 0x7FFF + ((u >> 16) & 1)) >> 16;   // RNE
  return (unsigned short)r;
}
__device__ __forceinline__ float bf2f(unsigned short h) {
  return __uint_as_float(((uint)h) << 16);
}

// ---------------------------------------------------------------------------
// Radix-4 Stockham DIF FFT, N=4096, 6 stages, autosort (verified r2/r3/r8).
// ---------------------------------------------------------------------------
template <int NT>
__device__ __forceinline__ void fft4096(float2* __restrict__ a,
                                        float2* __restrict__ b,
                                        const float2* __restrict__ tw, int tid) {
  float2* src = a;
  float2* dst = b;
#pragma unroll
  for (int s = 0; s < 12; s += 2) {
    const int m = 1 << s;
#pragma unroll
    for (int it = 0; it < 1024 / NT; ++it) {
      int idx = tid + it * NT;
      int i   = idx & (m - 1);
      int jm  = idx - i;
      float2 A0 = src[idx];
      float2 B0 = src[idx + 1024];
      float2 C0 = src[idx + 2048];
      float2 D0 = src[idx + 3072];
      float2 w1 = tw[jm];
      float2 w2 = make_float2(w1.x * w1.x - w1.y * w1.y, 2.f * w1.x * w1.y);
      float2 w3 = make_float2(w2.x * w1.x - w2.y * w1.y, w2.x * w1.y + w2.y * w1.x);
      float acx = A0.x + C0.x, acy = A0.y + C0.y;
      float amx = A0.x - C0.x, amy = A0.y - C0.y;
      float bdx = B0.x + D0.x, bdy = B0.y + D0.y;
      float bmx = B0.x - D0.x, bmy = B0.y - D0.y;
      float2 y0 = make_float2(acx + bdx, acy + bdy);
      float2 t2 = make_float2(acx - bdx, acy - bdy);
      float2 t1 = make_float2(amx + bmy, amy - bmx);
      float2 t3 = make_float2(amx - bmy, amy + bmx);
      int base = idx + 3 * jm;
      dst[base]         = y0;
      dst[base + m]     = make_float2(w1.x * t1.x - w1.y * t1.y, w1.x * t1.y + w1.y * t1.x);
      dst[base + 2 * m] = make_float2(w2.x * t2.x - w2.y * t2.y, w2.x * t2.y + w2.y * t2.x);
      dst[base + 3 * m] = make_float2(w3.x * t3.x - w3.y * t3.y, w3.x * t3.y + w3.y * t3.x);
    }
    __syncthreads();
    float2* t = src; src = dst; dst = t;
  }
}

template <int NT>
__device__ __forceinline__ void build_tw(float2* tw, int tid) {
  for (int t = tid; t < 1024; t += NT) {
    float ang = -(float)t * (6.283185307179586f / 4096.0f);
    float s, c;
    sincosf(ang, &s, &c);
    tw[t] = make_float2(c, s);
  }
}

// ---------------------------------------------------------------------------
// prep: bid<256: M[k][d][p] f32 -> Mt[k][p][d] bf16 (64x64 tiles)
//       bid>=256: u[b][l][d] f32 -> ubT[b][d][l] bf16 (64x64 tiles)
// (bodies identical to r8's verified tr_M / tr_u; merged to cut one launch)
// ---------------------------------------------------------------------------
__global__ __launch_bounds__(256) void prep(const float* __restrict__ M,
                                            const float* __restrict__ u,
                                            unsigned short* __restrict__ Mt,
                                            unsigned short* __restrict__ ubT) {
  __shared__ float t[64][65];
  const int bid = blockIdx.x;
  const int r = threadIdx.x >> 2, c0 = (threadIdx.x & 3) * 16;

  const float* src;
  unsigned short* dst;
  size_t src_stride;
  if (bid < 256) {                       // tr_M tile
    const int k = bid >> 4, d0 = ((bid >> 2) & 3) * 64, p0 = (bid & 3) * 64;
    src = M + ((size_t)k * 256 + d0) * 256 + p0;
    dst = Mt + ((size_t)k * 256 + p0 + r) * 256 + d0 + c0;
    src_stride = 256;
  } else {                               // tr_u tile
    const int b2 = bid - 256;
    const int l0 = (b2 & 63) * 64, d0 = ((b2 >> 6) & 3) * 64, plane = b2 >> 8;
    src = u + ((size_t)plane * 4096 + l0) * 256 + d0;
    dst = ubT + ((size_t)plane * 256 + d0 + r) * 4096 + l0 + c0;
    src_stride = 256;
  }
#pragma unroll
  for (int j = 0; j < 4; ++j) {
    float4 v = *(const float4*)(src + (size_t)r * src_stride + c0 + j * 4);
    t[r][c0 + j * 4 + 0] = v.x;
    t[r][c0 + j * 4 + 1] = v.y;
    t[r][c0 + j * 4 + 2] = v.z;
    t[r][c0 + j * 4 + 3] = v.w;
  }
  __syncthreads();
  u16x8 o0, o1;
#pragma unroll
  for (int j = 0; j < 8; ++j) o0[j] = f2bf(t[c0 + j][r]);
#pragma unroll
  for (int j = 0; j < 8; ++j) o1[j] = f2bf(t[c0 + 8 + j][r]);
  *(u16x8*)dst = o0;
  *(u16x8*)(dst + 8) = o1;
}

// ---------------------------------------------------------------------------
// Forward FFTs. bid<256: u d-pair (XCD-grouped so each Ut 64B line is written
// by one XCD). bid>=256: ev -> Hbuf.
// ---------------------------------------------------------------------------
__global__ __launch_bounds__(1024) void fft_fwd(const unsigned short* __restrict__ ubT,
                                                const float* __restrict__ ev,
                                                const float* __restrict__ lam,
                                                unsigned short* __restrict__ Ut,
                                                float* __restrict__ Hbuf) {
  __shared__ float2 A[4096];
  __shared__ float2 Bb[4096];
  __shared__ float2 tw[1024];
  const int tid = threadIdx.x;
  const int bid = blockIdx.x;
  build_tw<1024>(tw, tid);

  if (bid < 256) {
    const int plane = bid >> 7;
    const int jj = bid & 127;
    const int pair = (jj & 7) * 16 + (jj >> 3);   // XCD x -> pairs 16x..16x+15
    const int d0 = pair * 2;
    const unsigned short* r0 = ubT + ((size_t)plane * 256 + d0) * 4096;
    const unsigned short* r1 = r0 + 4096;
    const int l0 = tid * 4;
    ushort4 a4 = *(const ushort4*)(r0 + l0);
    ushort4 b4 = *(const ushort4*)(r1 + l0);
    A[l0 + 0] = make_float2(bf2f(a4.x), bf2f(b4.x));
    A[l0 + 1] = make_float2(bf2f(a4.y), bf2f(b4.y));
    A[l0 + 2] = make_float2(bf2f(a4.z), bf2f(b4.z));
    A[l0 + 3] = make_float2(bf2f(a4.w), bf2f(b4.w));
    __syncthreads();
    fft4096<1024>(A, Bb, tw, tid);
    unsigned short* Up = Ut + (size_t)plane * 4096 * 256 + d0;
#pragma unroll
    for (int i = 0; i < 2; ++i) {
      int f = tid + i * 1024;                     // 0..2047
      float u0x, u0y, u1x, u1y;
      if (f == 0) {
        float2 X0 = A[0], Xn = A[2048];
        u0x = X0.x; u1x = X0.y;                   // DC (real)
        u0y = Xn.x; u1y = Xn.y;                   // Nyquist -> im-slot 0
      } else {
        float2 Xa = A[f], Xb = A[4096 - f];
        u0x = 0.5f * (Xa.x + Xb.x);
        u0y = 0.5f * (Xa.y - Xb.y);
        u1x = 0.5f * (Xa.y + Xb.y);
        u1y = 0.5f * (Xb.x - Xa.x);
      }
      ushort2 re = make_ushort2(f2bf(u0x), f2bf(u1x));
      ushort2 im = make_ushort2(f2bf(u0y), f2bf(u1y));
      *(ushort2*)(Up + (size_t)f * 256)          = re;
      *(ushort2*)(Up + (size_t)(2048 + f) * 256) = im;
    }
  } else {
    const int k = bid - 256;
    const float* eb = ev + (size_t)k * 4096;
#pragma unroll
    for (int i = 0; i < 4; ++i) {
      int l = tid + i * 1024;
      A[l] = make_float2(eb[l], 0.0f);
    }
    __syncthreads();
    fft4096<1024>(A, Bb, tw, tid);
    const float sc = lam[k] * (1.0f / 4096.0f);
    float* Hp = Hbuf + (size_t)k * 4096;
#pragma unroll
    for (int i = 0; i < 2; ++i) {
      int f = tid + i * 1024;
      float2 X = A[f];
      Hp[f] = sc * X.x;
      Hp[2048 + f] = (f == 0) ? sc * A[2048].x : sc * X.y;
    }
  }
}

// ---------------------------------------------------------------------------
// Spectral GEMM + per-k complex filter accumulate.  512 threads, 8 waves.
// Waves 0-3: k=0..7; waves 4-7: k=8..15 (private Ms halves).
// U-fragments (k-INDEPENDENT) loaded once from global into 16 s16x8 regs:
//   frag kk, lane L: row = fb + w4*16 + (L&15) (+2048 for im),
//                    d = kk*32 + (L>>4)*8 .. +8    [same mapping the r8
//   swizzled-LDS path produced — index algebra: kc=kk*4+(L>>4), d=kc*8]
// End: LDS reduction of the two k-halves (scratch = Ms), waves 0-3 store.
// LDS: Ms 2x32K + Hlds 8K = 72K.
// ---------------------------------------------------------------------------
__global__ __launch_bounds__(512) void gemm_spec(const unsigned short* __restrict__ Ut,
                                                 const unsigned short* __restrict__ Mt,
                                                 const float* __restrict__ Hbuf,
                                                 float* __restrict__ Chat) {
  __shared__ unsigned short Ms[2][64 * 256];
  __shared__ float Hlds[16 * 128];
  // XCD-swizzled decode: each XCD gets 4 consecutive f-tiles x all p,plane
  const int gi  = blockIdx.x;
  const int xcd = gi & 7;
  const int gj  = gi >> 3;                  // 0..31
  const int fb    = (xcd * 4 + (gj & 3)) * 64;
  const int p0    = ((gj >> 2) & 3) * 64;
  const int plane = gj >> 4;

  const int tid  = threadIdx.x;
  const int lane = tid & 63;
  const int wave = tid >> 6;
  const int half = wave >> 2;               // k-half
  const int w4   = wave & 3;                // bin-group
  const int th   = tid & 255;

  // stage H for this f-tile: Hlds[k*128 + part*64 + j]
#pragma unroll
  for (int it = 0; it < 4; ++it) {
    int i2 = tid + it * 512;
    int k = i2 >> 7, rem = i2 & 127;
    Hlds[i2] = Hbuf[(size_t)k * 4096 + (rem >> 6) * 2048 + fb + (rem & 63)];
  }

  // U fragments -> registers (k-independent; held across the whole k-loop)
  const unsigned short* Up = Ut + (size_t)plane * 4096 * 256;
  const int binoff = w4 * 16 + (lane & 15);
  const int bin = fb + binoff;
  const int dly = (lane >> 4) * 8;
  s16x8 ure[8], uim[8];
#pragma unroll
  for (int kk = 0; kk < 8; ++kk) {
    ure[kk] = *(const s16x8*)(Up + (size_t)(fb + binoff) * 256 + kk * 32 + dly);
    uim[kk] = *(const s16x8*)(Up + (size_t)(2048 + fb + binoff) * 256 + kk * 32 + dly);
  }

  // prefetch M for this half's first k
  const unsigned short* Mbase = Mt + (size_t)half * 8 * 65536;
  u16x8 mreg[8];
#pragma unroll
  for (int it = 0; it < 8; ++it) {
    int cl = th + it * 256;
    int r = cl >> 5, c = cl & 31;
    mreg[it] = *(const u16x8*)(Mbase + (size_t)(p0 + r) * 256 + c * 8);
  }

  f32x4 cre[4], cim[4];
#pragma unroll
  for (int m = 0; m < 4; ++m) {
    cre[m] = (f32x4){0.f, 0.f, 0.f, 0.f};
    cim[m] = (f32x4){0.f, 0.f, 0.f, 0.f};
  }

  for (int kh = 0; kh < 8; ++kh) {
    if (kh > 0) __syncthreads();            // prev compute done with Ms
#pragma unroll
    for (int it = 0; it < 8; ++it) {
      int cl = th + it * 256;
      int r = cl >> 5, c = cl & 31;
      *(u16x8*)(&Ms[half][r * 256 + ((c ^ (r & 7)) * 8)]) = mreg[it];
    }
    if (kh < 7) {
      const unsigned short* Mk = Mbase + (size_t)(kh + 1) * 65536;
#pragma unroll
      for (int it = 0; it < 8; ++it) {
        int cl = th + it * 256;
        int r = cl >> 5, c = cl & 31;
        mreg[it] = *(const u16x8*)(Mk + (size_t)(p0 + r) * 256 + c * 8);
      }
    }
    __syncthreads();                        // Ms (and Hlds at kh=0) ready

    f32x4 are[4], aim[4];
#pragma unroll
    for (int m = 0; m < 4; ++m) {
      are[m] = (f32x4){0.f, 0.f, 0.f, 0.f};
      aim[m] = (f32x4){0.f, 0.f, 0.f, 0.f};
    }
#pragma unroll
    for (int kk = 0; kk < 8; ++kk) {
      const int kc = kk * 4 + (lane >> 4);
#pragma unroll
      for (int m = 0; m < 4; ++m) {
        int row = m * 16 + (lane & 15);
        s16x8 af = *(const s16x8*)(&Ms[half][row * 256 + ((kc ^ (row & 7)) * 8)]);
        are[m] = __builtin_amdgcn_mfma_f32_16x16x32_bf16(af, ure[kk], are[m], 0, 0, 0);
        aim[m] = __builtin_amdgcn_mfma_f32_16x16x32_bf16(af, uim[kk], aim[m], 0, 0, 0);
      }
    }
    const int k = kh + 8 * half;
    float hre = Hlds[k * 128 + binoff];
    float hs  = Hlds[k * 128 + 64 + binoff];
    bool sp = (bin == 0);                   // im slot holds Nyquist at bin 0
    float him = sp ? 0.0f : hs;
    float hA  = sp ? hs : hre;
#pragma unroll
    for (int m = 0; m < 4; ++m)
#pragma unroll
      for (int i = 0; i < 4; ++i) {
        cre[m][i] += hre * are[m][i] - him * aim[m][i];
        cim[m][i] += hA * aim[m][i] + him * are[m][i];
      }
  }

  // reduce the two k-halves via LDS (reuse Ms as 64KB float scratch)
  __syncthreads();
  float* Red = (float*)Ms;
#pragma unroll
  for (int m = 0; m < 4; ++m)
#pragma unroll
    for (int i = 0; i < 4; ++i) {
      Red[(m * 4 + i) * 512 + tid]        = cre[m][i];
      Red[(16 + m * 4 + i) * 512 + tid]   = cim[m][i];
    }
  __syncthreads();
  if (tid < 256) {
#pragma unroll
    for (int m = 0; m < 4; ++m)
#pragma unroll
      for (int i = 0; i < 4; ++i) {
        cre[m][i] += Red[(m * 4 + i) * 512 + tid + 256];
        cim[m][i] += Red[(16 + m * 4 + i) * 512 + tid + 256];
      }
    float* Cp = Chat + ((size_t)plane * 256 + p0) * 4096;
#pragma unroll
    for (int m = 0; m < 4; ++m)
#pragma unroll
      for (int i = 0; i < 4; ++i) {
        int pl = m * 16 + (lane >> 4) * 4 + i;
        Cp[(size_t)pl * 4096 + bin]        = cre[m][i];
        Cp[(size_t)pl * 4096 + 2048 + bin] = cim[m][i];
      }
  }
}

// ---------------------------------------------------------------------------
// Inverse: rebuild Hermitian spectra per p-pair, y = FFT(conj(C));
// write ytmp[plane][p][l] CONTIGUOUSLY (transpose to out happens after).
// ---------------------------------------------------------------------------
__global__ __launch_bounds__(1024) void ifft_store(const float* __restrict__ Chat,
                                                   float* __restrict__ ytmp) {
  __shared__ float2 A[4096];
  __shared__ float2 Bb[4096];
  __shared__ float2 tw[1024];
  const int tid = threadIdx.x;
  const int p0 = blockIdx.x * 2;
  const int plane = blockIdx.y;
  const float* C0 = Chat + ((size_t)plane * 256 + p0) * 4096;
  const float* C1 = C0 + 4096;
  build_tw<1024>(tw, tid);

  if (tid == 0) {
    A[0]    = make_float2(C0[0], -C1[0]);          // DC (real)
    A[2048] = make_float2(C0[2048], -C1[2048]);    // Nyquist (real)
  } else {
    int f = tid;                                   // 1..1023
    float cr0 = C0[f], ci0 = C0[2048 + f];
    float cr1 = C1[f], ci1 = C1[2048 + f];
    A[f]        = make_float2(cr0 - ci1, -(ci0 + cr1));
    A[4096 - f] = make_float2(cr0 + ci1, ci0 - cr1);
  }
  {
    int f = tid + 1024;                            // 1024..2047
    float cr0 = C0[f], ci0 = C0[2048 + f];
    float cr1 = C1[f], ci1 = C1[2048 + f];
    A[f]        = make_float2(cr0 - ci1, -(ci0 + cr1));
    A[4096 - f] = make_float2(cr0 + ci1, ci0 - cr1);
  }
  __syncthreads();
  fft4096<1024>(A, Bb, tw, tid);

  float* y0 = ytmp + ((size_t)plane * 256 + p0) * 4096;
  float* y1 = y0 + 4096;
#pragma unroll
  for (int i = 0; i < 4; ++i) {
    int l = tid + i * 1024;
    float2 g = A[l];
    y0[l] = g.x;
    y1[l] = -g.y;
  }
}

// ---------------------------------------------------------------------------
// ytmp[plane][p][l] -> out[plane][l][p]   (64x64 f32 tiles, coalesced)
// ---------------------------------------------------------------------------
__global__ __launch_bounds__(256) void tr_out(const float* __restrict__ ytmp,
                                              float* __restrict__ out) {
  __shared__ float t[64][65];
  const int l0 = blockIdx.x * 64, p0 = blockIdx.y * 64, plane = blockIdx.z;
  const int r = threadIdx.x >> 2, c0 = (threadIdx.x & 3) * 16;
  const float* src = ytmp + ((size_t)plane * 256 + p0 + r) * 4096 + l0;
#pragma unroll
  for (int j = 0; j < 4; ++j) {
    float4 v = *(const float4*)(src + c0 + j * 4);
    t[r][c0 + j * 4 + 0] = v.x;
    t[r][c0 + j * 4 + 1] = v.y;
    t[r][c0 + j * 4 + 2] = v.z;
    t[r][c0 + j * 4 + 3] = v.w;
  }
  __syncthreads();
  float* dst = out + ((size_t)plane * 4096 + l0 + r) * 256 + p0 + c0;
#pragma unroll
  for (int q = 0; q < 4; ++q) {
    float4 o;
    o.x = t[c0 + q * 4 + 0][r];
    o.y = t[c0 + q * 4 + 1][r];
    o.z = t[c0 + q * 4 + 2][r];
    o.w = t[c0 + q * 4 + 3][r];
    *(float4*)(dst + q * 4) = o;
  }
}

// ---------------------------------------------------------------------------
extern "C" void kernel_launch(void* const* d_in, const int* in_sizes, int n_in,
                              void* d_out, int out_size, void* d_ws,
                              size_t ws_size, hipStream_t stream) {
  const float* u   = (const float*)d_in[0];  // (2, 4096, 256)
  const float* ev  = (const float*)d_in[1];  // (16, 4096)
  const float* lam = (const float*)d_in[2];  // (16,)
  const float* M   = (const float*)d_in[3];  // (16, 256, 256)
  float* out = (float*)d_out;                // (2, 4096, 256)

  char* ws = (char*)d_ws;
  float* Hbuf         = (float*)ws;                          // 256 KB
  unsigned short* Mt  = (unsigned short*)(ws + (256 << 10)); // 2 MB
  unsigned short* ubT = (unsigned short*)(ws + (256 << 10) + (2 << 20));  // 4 MB
  unsigned short* Ut  = (unsigned short*)(ws + (256 << 10) + (6 << 20));  // 4 MB
  float* Chat         = (float*)(ws + (256 << 10) + (10 << 20));          // 8 MB
  float* ytmp         = (float*)(ws + (256 << 10) + (18 << 20));          // 8 MB

  prep<<<768, 256, 0, stream>>>(M, u, Mt, ubT);
  fft_fwd<<<272, 1024, 0, stream>>>(ubT, ev, lam, Ut, Hbuf);
  gemm_spec<<<256, 512, 0, stream>>>(Ut, Mt, Hbuf, Chat);
  ifft_store<<<dim3(128, 2), 1024, 0, stream>>>(Chat, ytmp);
  tr_out<<<dim3(64, 4, 2), 256, 0, stream>>>(ytmp, out);
}